// Round 23
// baseline (149.169 us; speedup 1.0000x reference)
//
#include <hip/hip_runtime.h>
#include <hip/hip_bf16.h>
#include <math.h>

#define NCAP 10
#define DCAP 16
#define DIN  128
#define NPOS 4096
#define NB   64

typedef short short8 __attribute__((ext_vector_type(8)));
typedef float floatx4 __attribute__((ext_vector_type(4)));

__device__ inline float bflo(unsigned v) { return __uint_as_float(v << 16); }
__device__ inline float bfhi(unsigned v) { return __uint_as_float(v & 0xFFFF0000u); }
__device__ inline unsigned short f2bf(float f) {           // round-to-nearest-even
    unsigned u = __float_as_uint(f);
    return (unsigned short)((u + 0x7FFFu + ((u >> 16) & 1u)) >> 16);
}

// ===========================================================================
// ws layout (22.4 MB):
//   partial : f32 [64][32][128]     @ 0           (col-sum partials, 1 MB)
//   pws     : f32 [64][32][10][128] @ 1,048,576   (iter-2 PV partials)
//   pws2    : f32 [64][32][10][128] @ 11,534,336  (iter-3 PV partials)
// 4 dispatches: caps_sum -> route_fused<0> -> route_fused<1> -> small2.
// The v->w "small" kernels are folded into the route passes: each block
// redundantly computes w[10][128] for its batch (identical op order in all
// blocks -> deterministic, bit-identical w). NO cooperative launch (R22
// lesson: grid.sync deadlocks under this harness).
// ===========================================================================

// Pass A: per-batch column sums of u (read-only). 128 pos per block.
__global__ __launch_bounds__(256) void caps_sum(const float* __restrict__ u,
                                                float* __restrict__ partial) {
    const int b = blockIdx.x;
    const int chunk = blockIdx.y;          // 32 chunks of 128 positions
    const int t = threadIdx.x;
    const int v4 = t & 31;
    const int prow = t >> 5;
    const float4* up = (const float4*)u;
    const size_t posbase = (size_t)b * NPOS + chunk * 128;

    float4 acc = make_float4(0.f, 0.f, 0.f, 0.f);
    #pragma unroll 8
    for (int j = 0; j < 16; ++j) {
        const size_t idx = (posbase + prow + j * 8) * 32 + v4;
        float4 x = up[idx];
        acc.x += x.x; acc.y += x.y; acc.z += x.z; acc.w += x.w;
    }
    __shared__ float4 red[8][32];
    red[prow][v4] = acc;
    __syncthreads();
    if (t < 32) {
        float4 s = red[0][t];
        #pragma unroll
        for (int r = 1; r < 8; ++r) {
            s.x += red[r][t].x; s.y += red[r][t].y;
            s.z += red[r][t].z; s.w += red[r][t].w;
        }
        ((float4*)partial)[((size_t)(b * 32 + chunk)) * 32 + t] = s;
    }
}

// Routing pass with fused in-block w computation.
// SRC==0: w from partial (colsum, 0.1 softmax scale). SRC==1: w from pws.
// Then verbatim R21 route body: stage f32->bf16 swizzled LDS, MFMA logits,
// in-lane softmax, broadcast-p2, 4-quarter fold, one coalesced pdst store.
template <int SRC>
__global__ __launch_bounds__(256) void route_fused(const float* __restrict__ u,
                                                   const float* __restrict__ src,
                                                   const float* __restrict__ W,
                                                   float* __restrict__ pdst) {
    const int b = blockIdx.x;
    const int g = blockIdx.y;              // 32 groups of 128 positions
    const int t = threadIdx.x;
    const int l = t & 63;
    const int w = __builtin_amdgcn_readfirstlane(t >> 6);

    __shared__ __align__(16) char smem[23552];
    uint4* tile = (uint4*)smem;                         // [64][16] uint4, 16 KB
    float (*csm)[12] = (float (*)[12])(smem + 16384);   // [64][12], 3 KB
    float* xvf  = (float*)smem;                         // phase W: <=1280 f
    float* wlds = (float*)(smem + 5120);                // phase W: 1280 f
    float* vv   = (float*)(smem + 10240);               // phase W: 160 f

    // ---- phase W: fold src -> s -> squash -> v -> w[10][128] (in LDS) ----
    if (SRC == 0) {
        if (t < 128) {
            float a = 0.f;
            #pragma unroll 8
            for (int c = 0; c < 32; ++c)
                a += src[(size_t)(b * 32 + c) * DIN + t];
            xvf[t] = a;
        }
    } else {
        #pragma unroll
        for (int o = 0; o < 5; ++o) {
            const int k = o * 256 + t;
            float a = 0.f;
            #pragma unroll 8
            for (int c = 0; c < 32; ++c)
                a += src[(size_t)(b * 32 + c) * 1280 + k];
            xvf[k] = a;
        }
    }
    __syncthreads();
    if (t < 160) {
        const int n = t >> 4, j = t & 15;
        const float* xb = (SRC == 0) ? xvf : (xvf + n * 128);
        float sv = 0.f;
        for (int d = 0; d < DIN; ++d)
            sv = fmaf(xb[d], W[d * 160 + n * DCAP + j], sv);
        if (SRC == 0) sv *= 0.1f;          // uniform softmax on iter 1
        float nq = sv * sv;
        #pragma unroll
        for (int mm = 8; mm >= 1; mm >>= 1) nq += __shfl_xor(nq, mm, 16);
        nq += 1e-7f;
        vv[t] = sv * sqrtf(nq) / (1.0f + nq);
    }
    __syncthreads();
    #pragma unroll
    for (int o = 0; o < 5; ++o) {
        const int k = o * 256 + t;
        const int n = k >> 7, d = k & 127;
        float wd = 0.f;
        #pragma unroll
        for (int j = 0; j < DCAP; ++j)
            wd = fmaf(W[d * 160 + n * DCAP + j], vv[n * DCAP + j], wd);
        wlds[k] = wd;
    }
    __syncthreads();

    // ---- A-frags from wlds (f32 -> bf16); rows 10..15 zero ----
    const int an = l & 15;
    short8 af[4];
    #pragma unroll
    for (int kk = 0; kk < 4; ++kk) {
        short8 a = {0, 0, 0, 0, 0, 0, 0, 0};
        if (an < 10) {
            const float* wb = wlds + an * 128 + (kk * 4 + (l >> 4)) * 8;
            const float4 x0 = *(const float4*)wb;
            const float4 x1 = *(const float4*)(wb + 4);
            a[0] = (short)f2bf(x0.x); a[1] = (short)f2bf(x0.y);
            a[2] = (short)f2bf(x0.z); a[3] = (short)f2bf(x0.w);
            a[4] = (short)f2bf(x1.x); a[5] = (short)f2bf(x1.y);
            a[6] = (short)f2bf(x1.z); a[7] = (short)f2bf(x1.w);
        }
        af[kk] = a;
    }

    const int d2 = t & 63;                 // dim-pair {2*d2, 2*d2+1}
    float acc[NCAP][2];
    #pragma unroll
    for (int n = 0; n < NCAP; ++n) { acc[n][0] = 0.f; acc[n][1] = 0.f; }

    for (int s = 0; s < 2; ++s) {
        __syncthreads();                   // af in regs; tile safe to overwrite
        // ---- stage: f32 reads (coalesced) -> bf16 -> swizzled LDS ----
        const float4* src4 = (const float4*)u +
            ((size_t)b * NPOS + g * 128 + s * 64) * 32;
        #pragma unroll
        for (int i = 0; i < 4; ++i) {
            const int q = t + i * 256;
            const int r = q >> 4, c = q & 15;
            const float4 x0 = src4[r * 32 + c * 2];
            const float4 x1 = src4[r * 32 + c * 2 + 1];
            uint4 h;
            h.x = (unsigned)f2bf(x0.x) | ((unsigned)f2bf(x0.y) << 16);
            h.y = (unsigned)f2bf(x0.z) | ((unsigned)f2bf(x0.w) << 16);
            h.z = (unsigned)f2bf(x1.x) | ((unsigned)f2bf(x1.y) << 16);
            h.w = (unsigned)f2bf(x1.z) | ((unsigned)f2bf(x1.w) << 16);
            tile[r * 16 + (c ^ (r & 7))] = h;
        }
        __syncthreads();

        // ---- logits via MFMA (R20/R21-verified layout) ----
        floatx4 lg = {0.f, 0.f, 0.f, 0.f};
        #pragma unroll
        for (int kk = 0; kk < 4; ++kk) {
            const int br = w * 16 + (l & 15);
            const int q = kk * 4 + (l >> 4);
            const short8 bf = *(const short8*)&tile[br * 16 + (q ^ (br & 7))];
            lg = __builtin_amdgcn_mfma_f32_16x16x32_bf16(af[kk], bf, lg, 0, 0, 0);
        }

        // ---- softmax over n ----
        const int ng = (l >> 4) * 4;
        float m = -1e30f;
        #pragma unroll
        for (int r2 = 0; r2 < 4; ++r2)
            if (ng + r2 < 10) m = fmaxf(m, lg[r2]);
        m = fmaxf(m, __shfl_xor(m, 16));
        m = fmaxf(m, __shfl_xor(m, 32));
        float e[4];
        float ss = 0.f;
        #pragma unroll
        for (int r2 = 0; r2 < 4; ++r2) {
            e[r2] = (ng + r2 < 10) ? __expf(lg[r2] - m) : 0.f;
            ss += e[r2];
        }
        ss += __shfl_xor(ss, 16);
        ss += __shfl_xor(ss, 32);
        const float inv = 1.0f / ss;
        const int posl = w * 16 + (l & 15);
        #pragma unroll
        for (int r2 = 0; r2 < 4; ++r2)
            if (ng + r2 < 10) csm[posl][ng + r2] = e[r2] * inv;
        __syncthreads();

        // ---- p2: wave w owns pos [16w,16w+16); lanes share p (broadcast) ----
        const unsigned* tlu = (const unsigned*)tile;
        #pragma unroll 4
        for (int i = 0; i < 16; ++i) {
            const int p = w * 16 + i;
            const unsigned v = tlu[(p * 16 + ((d2 >> 2) ^ (p & 7))) * 4 + (d2 & 3)];
            const float f0 = bflo(v), f1 = bfhi(v);
            const float4 c03 = *(const float4*)&csm[p][0];
            const float4 c47 = *(const float4*)&csm[p][4];
            const float2 c89 = *(const float2*)&csm[p][8];
            acc[0][0] = fmaf(c03.x, f0, acc[0][0]); acc[0][1] = fmaf(c03.x, f1, acc[0][1]);
            acc[1][0] = fmaf(c03.y, f0, acc[1][0]); acc[1][1] = fmaf(c03.y, f1, acc[1][1]);
            acc[2][0] = fmaf(c03.z, f0, acc[2][0]); acc[2][1] = fmaf(c03.z, f1, acc[2][1]);
            acc[3][0] = fmaf(c03.w, f0, acc[3][0]); acc[3][1] = fmaf(c03.w, f1, acc[3][1]);
            acc[4][0] = fmaf(c47.x, f0, acc[4][0]); acc[4][1] = fmaf(c47.x, f1, acc[4][1]);
            acc[5][0] = fmaf(c47.y, f0, acc[5][0]); acc[5][1] = fmaf(c47.y, f1, acc[5][1]);
            acc[6][0] = fmaf(c47.z, f0, acc[6][0]); acc[6][1] = fmaf(c47.z, f1, acc[6][1]);
            acc[7][0] = fmaf(c47.w, f0, acc[7][0]); acc[7][1] = fmaf(c47.w, f1, acc[7][1]);
            acc[8][0] = fmaf(c89.x, f0, acc[8][0]); acc[8][1] = fmaf(c89.x, f1, acc[8][1]);
            acc[9][0] = fmaf(c89.y, f0, acc[9][0]); acc[9][1] = fmaf(c89.y, f1, acc[9][1]);
        }
    }

    // ---- fold 4 pos-quarter partials (reuse tile+csm region), store ----
    __syncthreads();                       // all p2 reads done
    float* red = (float*)smem;             // [4][1280] f32 = 20480 B
    #pragma unroll
    for (int n = 0; n < NCAP; ++n) {
        red[w * 1280 + n * 128 + d2 * 2]     = acc[n][0];
        red[w * 1280 + n * 128 + d2 * 2 + 1] = acc[n][1];
    }
    __syncthreads();
    float* pb = pdst + (size_t)(b * 32 + g) * 1280;
    #pragma unroll
    for (int o = 0; o < 5; ++o) {
        const int k = o * 256 + t;
        pb[k] = red[k] + red[1280 + k] + red[2560 + k] + red[3840 + k];
    }
}

// Final: fold pws2 -> s -> squash -> out [64][10][16].
__global__ __launch_bounds__(128) void small_out(const float* __restrict__ src,
                                                 const float* __restrict__ W,
                                                 float* __restrict__ out) {
    const int b = blockIdx.x / NCAP;
    const int n = blockIdx.x % NCAP;
    const int t = threadIdx.x;
    __shared__ float xv[DIN];

    float a = 0.f;
    #pragma unroll 8
    for (int c = 0; c < 32; ++c)
        a += src[((size_t)(b * 32 + c) * NCAP + n) * DIN + t];
    xv[t] = a;
    __syncthreads();

    if (t < DCAP) {
        float sv = 0.f;
        for (int d = 0; d < DIN; ++d)
            sv = fmaf(xv[d], W[d * 160 + n * DCAP + t], sv);
        float nq = sv * sv;
        #pragma unroll
        for (int mm = 8; mm >= 1; mm >>= 1) nq += __shfl_xor(nq, mm, 16);
        nq += 1e-7f;
        out[(size_t)(b * NCAP + n) * DCAP + t] = sv * sqrtf(nq) / (1.0f + nq);
    }
}

extern "C" void kernel_launch(void* const* d_in, const int* in_sizes, int n_in,
                              void* d_out, int out_size, void* d_ws, size_t ws_size,
                              hipStream_t stream) {
    const float* u = (const float*)d_in[0];   // [64][4096][128]
    const float* W = (const float*)d_in[1];   // [128][160]
    float* out = (float*)d_out;               // [64][10][16]
    char* wsb = (char*)d_ws;

    float* partial = (float*)wsb;                       // 1 MB
    float* pws     = (float*)(wsb + 1048576);           // 10.5 MB
    float* pws2    = (float*)(wsb + 11534336);          // 10.5 MB

    caps_sum<<<dim3(NB, 32), 256, 0, stream>>>(u, partial);
    route_fused<0><<<dim3(NB, 32), 256, 0, stream>>>(u, partial, W, pws);  // iter 2
    route_fused<1><<<dim3(NB, 32), 256, 0, stream>>>(u, pws, W, pws2);     // iter 3
    small_out<<<NB * NCAP, 128, 0, stream>>>(pws2, W, out);                // v3 -> out
}